// Round 2
// baseline (117.109 us; speedup 1.0000x reference)
//
#include <hip/hip_runtime.h>
#include <cmath>

constexpr int   DIM   = 2048;
constexpr int   NEXP  = 4;
constexpr float EPS   = 1e-6f;
constexpr float SCALE = 3.0f;

// One wave (64 lanes) per PAIR of rows. Fused router weight rw[e][d]*nw[d]
// staged in LDS (32 KiB/block) so VGPRs stay < 128 -> 4 waves/SIMD.
// Each lane covers 32 elements per row (8 x float4 at d = k*256 + lane*4);
// 2 rows per iteration = 16 independent global float4 loads in flight and
// each LDS weight read feeds both rows. 10 partials (2 x (sumsq + 4 dots))
// reduced with one 64-lane xor-shuffle butterfly; lane 0 stores 2 float4.
__global__ __launch_bounds__(256, 4)
void altup_router_kernel(const float* __restrict__ x,
                         const float* __restrict__ nw,
                         const float* __restrict__ rw,
                         float* __restrict__ out,
                         int nrows)
{
    __shared__ float wlds[NEXP * DIM];  // 32 KiB

    const int tid = threadIdx.x;

    // Stage fused weights: 8192 floats, 256 threads -> 8 float4 each.
    for (int i = tid * 4; i < NEXP * DIM; i += 256 * 4) {
        const int d = i & (DIM - 1);
        const float4 r = *reinterpret_cast<const float4*>(rw + i);
        const float4 n = *reinterpret_cast<const float4*>(nw + d);
        *reinterpret_cast<float4*>(wlds + i) =
            make_float4(r.x * n.x, r.y * n.y, r.z * n.z, r.w * n.w);
    }
    __syncthreads();

    const int lane   = tid & 63;
    const int wid    = tid >> 6;
    const int nwaves = gridDim.x * (blockDim.x >> 6);
    const int wave   = blockIdx.x * (blockDim.x >> 6) + wid;
    const int base   = lane * 4;

    const int npairs = (nrows + 1) >> 1;

    for (int pr = wave; pr < npairs; pr += nwaves) {
        const int row  = pr * 2;
        const bool two = (row + 1) < nrows;

        const float* xr0 = x + (size_t)row * DIM;
        const float* xr1 = xr0 + (two ? DIM : 0);  // safe alias if odd tail

        float acc[10] = {0.f};  // [0..4]=row0 sumsq+dots, [5..9]=row1

#pragma unroll
        for (int k = 0; k < 8; ++k) {
            const int d = k * 256 + base;
            const float4 a = *reinterpret_cast<const float4*>(xr0 + d);
            const float4 b = *reinterpret_cast<const float4*>(xr1 + d);

            acc[0] = fmaf(a.x, a.x, acc[0]);
            acc[0] = fmaf(a.y, a.y, acc[0]);
            acc[0] = fmaf(a.z, a.z, acc[0]);
            acc[0] = fmaf(a.w, a.w, acc[0]);
            acc[5] = fmaf(b.x, b.x, acc[5]);
            acc[5] = fmaf(b.y, b.y, acc[5]);
            acc[5] = fmaf(b.z, b.z, acc[5]);
            acc[5] = fmaf(b.w, b.w, acc[5]);

#pragma unroll
            for (int e = 0; e < NEXP; ++e) {
                const float4 w = *reinterpret_cast<const float4*>(wlds + e * DIM + d);
                acc[1 + e] = fmaf(a.x, w.x, acc[1 + e]);
                acc[1 + e] = fmaf(a.y, w.y, acc[1 + e]);
                acc[1 + e] = fmaf(a.z, w.z, acc[1 + e]);
                acc[1 + e] = fmaf(a.w, w.w, acc[1 + e]);
                acc[6 + e] = fmaf(b.x, w.x, acc[6 + e]);
                acc[6 + e] = fmaf(b.y, w.y, acc[6 + e]);
                acc[6 + e] = fmaf(b.z, w.z, acc[6 + e]);
                acc[6 + e] = fmaf(b.w, w.w, acc[6 + e]);
            }
        }

        // 64-lane butterfly reduction of the 10 partials
#pragma unroll
        for (int m = 32; m >= 1; m >>= 1) {
#pragma unroll
            for (int i = 0; i < 10; ++i)
                acc[i] += __shfl_xor(acc[i], m, 64);
        }

        if (lane == 0) {
            const float ir0 = rsqrtf(acc[0] * (1.0f / DIM) + EPS);
            float4 o0;
            o0.x = tanhf(acc[1] * ir0 * SCALE);
            o0.y = tanhf(acc[2] * ir0 * SCALE);
            o0.z = tanhf(acc[3] * ir0 * SCALE);
            o0.w = tanhf(acc[4] * ir0 * SCALE);
            reinterpret_cast<float4*>(out)[row] = o0;

            if (two) {
                const float ir1 = rsqrtf(acc[5] * (1.0f / DIM) + EPS);
                float4 o1;
                o1.x = tanhf(acc[6] * ir1 * SCALE);
                o1.y = tanhf(acc[7] * ir1 * SCALE);
                o1.z = tanhf(acc[8] * ir1 * SCALE);
                o1.w = tanhf(acc[9] * ir1 * SCALE);
                reinterpret_cast<float4*>(out)[row + 1] = o1;
            }
        }
    }
}

extern "C" void kernel_launch(void* const* d_in, const int* in_sizes, int n_in,
                              void* d_out, int out_size, void* d_ws, size_t ws_size,
                              hipStream_t stream)
{
    const float* x   = (const float*)d_in[0];  // (4, 8192, 2048) f32
    const float* nw  = (const float*)d_in[1];  // (2048,) f32
    const float* rw  = (const float*)d_in[2];  // (4, 2048) f32
    float*       out = (float*)d_out;          // (4, 8192, 4) f32

    const int nrows  = in_sizes[0] / DIM;      // 32768
    const int npairs = (nrows + 1) >> 1;       // 16384

    // 512 blocks x 4 waves = 2048 waves (fills 256 CU x 2 blocks x 4 waves);
    // each wave handles ~8 row-pairs. Shrink grid for tiny inputs.
    int blocks = 512;
    const int max_blocks = (npairs + 3) / 4;
    if (blocks > max_blocks) blocks = max_blocks;
    if (blocks < 1) blocks = 1;

    hipLaunchKernelGGL(altup_router_kernel, dim3(blocks), dim3(256), 0, stream,
                       x, nw, rw, out, nrows);
}

// Round 4
// 49.949 us; speedup vs baseline: 2.3446x; 2.3446x over previous
//
#include <hip/hip_runtime.h>
#include <cmath>

constexpr int   DIM   = 2048;
constexpr int   NEXP  = 4;
constexpr float EPS   = 1e-6f;
constexpr float SCALE = 3.0f;

// Native clang vector type: __builtin_nontemporal_load requires scalar /
// pointer / native-vector element pointers (HIP float4 is a struct -> rejected).
typedef float f32x4 __attribute__((ext_vector_type(4)));

// One wave (64 lanes) per PAIR of rows. Fused router weight rw[e][d]*nw[d]
// held in REGISTERS (128 VGPR) -- R2 showed LDS weights serialize load issue.
// Per pair-iteration: 16 nontemporal float4 loads issued as one cluster
// (~215 VGPR total, 2 waves/SIMD = 8 waves/CU), then 80 FMAs, then ONE
// 6-step xor-shuffle butterfly over 10 partials (tail amortized over 2 rows).
__global__ __launch_bounds__(256, 2)
void altup_router_kernel(const float* __restrict__ x,
                         const float* __restrict__ nw,
                         const float* __restrict__ rw,
                         float* __restrict__ out,
                         int nrows)
{
    const int tid    = threadIdx.x;
    const int lane   = tid & 63;
    const int wid    = tid >> 6;
    const int nwaves = gridDim.x * (blockDim.x >> 6);
    const int wave   = blockIdx.x * (blockDim.x >> 6) + wid;
    const int base   = lane * 4;  // float offset inside each 256-float chunk

    // Preload fused weights: w[e][k] = rw[e*DIM + d] * nw[d]
    f32x4 w[NEXP][8];
#pragma unroll
    for (int e = 0; e < NEXP; ++e) {
#pragma unroll
        for (int k = 0; k < 8; ++k) {
            const int d = k * 256 + base;
            const f32x4 r = *reinterpret_cast<const f32x4*>(rw + e * DIM + d);
            const f32x4 n = *reinterpret_cast<const f32x4*>(nw + d);
            w[e][k] = r * n;
        }
    }

    const int npairs = (nrows + 1) >> 1;

    for (int pr = wave; pr < npairs; pr += nwaves) {
        const int row  = pr * 2;
        const bool two = (row + 1) < nrows;

        const float* xr0 = x + (size_t)row * DIM;
        const float* xr1 = xr0 + (two ? DIM : 0);  // safe alias on odd tail

        // Issue all 16 loads back-to-back (single-use stream -> nontemporal).
        f32x4 av[8], bv[8];
#pragma unroll
        for (int k = 0; k < 8; ++k) {
            const int d = k * 256 + base;
            av[k] = __builtin_nontemporal_load(
                        reinterpret_cast<const f32x4*>(xr0 + d));
            bv[k] = __builtin_nontemporal_load(
                        reinterpret_cast<const f32x4*>(xr1 + d));
        }

        float acc[10] = {0.f};  // [0..4]=row0 sumsq+dots, [5..9]=row1
#pragma unroll
        for (int k = 0; k < 8; ++k) {
            const f32x4 a = av[k];
            const f32x4 b = bv[k];

#pragma unroll
            for (int j = 0; j < 4; ++j) {
                acc[0] = fmaf(a[j], a[j], acc[0]);
                acc[5] = fmaf(b[j], b[j], acc[5]);
            }

#pragma unroll
            for (int e = 0; e < NEXP; ++e) {
                const f32x4 we = w[e][k];
#pragma unroll
                for (int j = 0; j < 4; ++j) {
                    acc[1 + e] = fmaf(a[j], we[j], acc[1 + e]);
                    acc[6 + e] = fmaf(b[j], we[j], acc[6 + e]);
                }
            }
        }

        // One 64-lane butterfly for both rows' partials.
#pragma unroll
        for (int m = 32; m >= 1; m >>= 1) {
#pragma unroll
            for (int i = 0; i < 10; ++i)
                acc[i] += __shfl_xor(acc[i], m, 64);
        }

        if (lane == 0) {
            const float ir0 = rsqrtf(acc[0] * (1.0f / DIM) + EPS);
            f32x4 o0;
            o0.x = tanhf(acc[1] * ir0 * SCALE);
            o0.y = tanhf(acc[2] * ir0 * SCALE);
            o0.z = tanhf(acc[3] * ir0 * SCALE);
            o0.w = tanhf(acc[4] * ir0 * SCALE);
            reinterpret_cast<f32x4*>(out)[row] = o0;

            if (two) {
                const float ir1 = rsqrtf(acc[5] * (1.0f / DIM) + EPS);
                f32x4 o1;
                o1.x = tanhf(acc[6] * ir1 * SCALE);
                o1.y = tanhf(acc[7] * ir1 * SCALE);
                o1.z = tanhf(acc[8] * ir1 * SCALE);
                o1.w = tanhf(acc[9] * ir1 * SCALE);
                reinterpret_cast<f32x4*>(out)[row + 1] = o1;
            }
        }
    }
}

extern "C" void kernel_launch(void* const* d_in, const int* in_sizes, int n_in,
                              void* d_out, int out_size, void* d_ws, size_t ws_size,
                              hipStream_t stream)
{
    const float* x   = (const float*)d_in[0];  // (4, 8192, 2048) f32
    const float* nw  = (const float*)d_in[1];  // (2048,) f32
    const float* rw  = (const float*)d_in[2];  // (4, 2048) f32
    float*       out = (float*)d_out;          // (4, 8192, 4) f32

    const int nrows  = in_sizes[0] / DIM;      // 32768
    const int npairs = (nrows + 1) >> 1;       // 16384

    // Persistent grid: 512 blocks x 4 waves = 2048 waves = exactly 8 waves/CU
    // (the occupancy cap at ~215 VGPR). Each wave walks ~8 row-pairs.
    int blocks = 512;
    const int max_blocks = (npairs + 3) / 4;
    if (blocks > max_blocks) blocks = max_blocks;
    if (blocks < 1) blocks = 1;

    hipLaunchKernelGGL(altup_router_kernel, dim3(blocks), dim3(256), 0, stream,
                       x, nw, rw, out, nrows);
}